// Round 11
// baseline (5966.831 us; speedup 1.0000x reference)
//
#include <hip/hip_runtime.h>
#include <hip/hip_bf16.h>
#include <cstddef>

#define S_LEN 512
#define BATCH 64
#define HID 256
#define G3 768
#define SB (S_LEN*BATCH)
#define D2 512
#define L2E 1.44269504f

typedef unsigned short u16;
typedef __attribute__((ext_vector_type(8))) short s16x8;
typedef __attribute__((ext_vector_type(8))) _Float16 f16x8;
typedef __attribute__((ext_vector_type(4))) float f32x4;

__device__ __forceinline__ float bf2f(u16 u) {
    return __uint_as_float(((unsigned)u) << 16);
}
__device__ __forceinline__ u16 f2bf(float f) {
    unsigned u = __float_as_uint(f);
    unsigned r = (u + 0x7FFFu + ((u >> 16) & 1u)) >> 16;
    return (u16)r;
}
__device__ __forceinline__ float fast_rcp(float x) {
#if __has_builtin(__builtin_amdgcn_rcpf)
    return __builtin_amdgcn_rcpf(x);
#else
    return 1.f / x;
#endif
}
__device__ __forceinline__ float fast_exp2(float x) {
#if __has_builtin(__builtin_amdgcn_exp2f)
    return __builtin_amdgcn_exp2f(x);
#else
    return __expf(x * 0.69314718f);
#endif
}
__device__ __forceinline__ void gload_lds16(const void* g, void* l) {
    __builtin_amdgcn_global_load_lds((const __attribute__((address_space(1))) void*)g,
                                     (__attribute__((address_space(3))) void*)l, 16, 0, 0);
}

// ---------- prep kernels ----------
__global__ void f32_to_bf16(const float* __restrict__ in, u16* __restrict__ out, long n) {
    long i = (long)blockIdx.x * 256 + threadIdx.x;
    if (i < n) out[i] = f2bf(in[i]);
}
// w_ih scaled: gate rows g<512 ×log2e, g>=512 ×2log2e (exp2 prescale)
__global__ void f32_to_bf16_gs(const float* __restrict__ in, u16* __restrict__ out,
                               long n, int K) {
    long i = (long)blockIdx.x * 256 + threadIdx.x;
    if (i >= n) return;
    int g = (int)((i / K) % 768);
    float sc = (g < 512) ? L2E : (2.f * L2E);
    out[i] = f2bf(in[i] * sc);
}
// w_hh -> f16 native layout [12][768][256], exp2-prescaled per gate
__global__ void f32_to_f16_gs(const float* __restrict__ in, _Float16* __restrict__ out, long n) {
    long i = (long)blockIdx.x * 256 + threadIdx.x;
    if (i >= n) return;
    int g = (int)((i / 256) % 768);
    float sc = (g < 512) ? L2E : (2.f * L2E);
    out[i] = (_Float16)(in[i] * sc);
}
// biasT[l][d][g]: g<512 -> (b_ih+b_hh)*log2e ; g>=512 -> b_ih*2log2e
__global__ void add_bias(const float* __restrict__ bih0, const float* __restrict__ bihl,
                         const float* __restrict__ bhh, float* __restrict__ outb) {
    int i = blockIdx.x * 256 + threadIdx.x;
    if (i >= 6 * 1536) return;
    int l = i / 1536, r = i - l * 1536;
    int g = r % 768;
    float bi = (l == 0) ? bih0[r] : bihl[(l - 1) * 1536 + r];
    outb[i] = (g < 512) ? (bi + bhh[i]) * L2E : bi * (2.f * L2E);
}

// ---------- input GEMM (MFMA) ----------
__global__ __launch_bounds__(256, 2) void gemm_mfma(
    const u16* __restrict__ A,
    const u16* __restrict__ Bt,
    const float* __restrict__ bias,
    u16* __restrict__ Cg,
    int K)
{
    int d = blockIdx.z;
    const u16* Bb = Bt + (size_t)d * 768 * K;
    const float* bi = bias + d * G3;
    u16* Cm = Cg + (size_t)d * SB * G3;

    int n0 = blockIdx.x * 128;
    int m0 = blockIdx.y * 128;
    int tid = threadIdx.x;
    int wave = tid >> 6, lane = tid & 63;
    int wm = wave >> 1, wn = wave & 1;

    __shared__ u16 Asm[128 * 32];
    __shared__ u16 Bsm[128 * 32];

    f32x4 acc[4][4] = {};

    for (int k0 = 0; k0 < K; k0 += 32) {
#pragma unroll
        for (int p = 0; p < 2; p++) {
            int c = p * 256 + wave * 64 + lane;
            int row = c >> 2, kc = c & 3;
            const u16* srcA = A + (size_t)(m0 + row) * K + k0 + kc * 8;
            const u16* srcB = Bb + (size_t)(n0 + row) * K + k0 + kc * 8;
            gload_lds16(srcA, &Asm[(p * 256 + wave * 64) * 8]);
            gload_lds16(srcB, &Bsm[(p * 256 + wave * 64) * 8]);
        }
        __syncthreads();

        s16x8 af[4], bfr[4];
#pragma unroll
        for (int i = 0; i < 4; i++) {
            int arow = wm * 64 + i * 16 + (lane & 15);
            af[i] = *reinterpret_cast<const s16x8*>(&Asm[arow * 32 + (lane >> 4) * 8]);
            int brow = wn * 64 + i * 16 + (lane & 15);
            bfr[i] = *reinterpret_cast<const s16x8*>(&Bsm[brow * 32 + (lane >> 4) * 8]);
        }
#pragma unroll
        for (int i = 0; i < 4; i++)
#pragma unroll
            for (int j = 0; j < 4; j++)
                acc[i][j] = __builtin_amdgcn_mfma_f32_16x16x32_bf16(af[i], bfr[j], acc[i][j], 0, 0, 0);
        __syncthreads();
    }

    int lcol = lane & 15, lrow4 = (lane >> 4) * 4;
#pragma unroll
    for (int i = 0; i < 4; i++) {
#pragma unroll
        for (int j = 0; j < 4; j++) {
            int n = n0 + wn * 64 + j * 16 + lcol;
            float bv = bi[n];
#pragma unroll
            for (int q = 0; q < 4; q++) {
                int m = m0 + wm * 64 + i * 16 + lrow4 + q;
                Cm[(size_t)m * G3 + n] = f2bf(acc[i][j][q] + bv);
            }
        }
    }
}

// ---------- MFMA recurrent scan (R7 skeleton + pinned weights) ----------
// 8 blocks (4 batch-groups x 2 dirs) x 512 threads (8 waves).
// Wave wv owns columns c0 = wv*16+lr and c1 = c0+128, ALL 3 gates in-lane.
// Weights: 48 B-frags = 192 VGPRs, asm-pinned (no remat). ONE barrier/step.
// gi: PROVEN R7 staging (3x gload_lds16/wave into linear [16][768] rows).
__global__ __launch_bounds__(512, 2) void scan_mfma(
    const _Float16* __restrict__ whh16,  // [12][768][256] f16, exp2-prescaled
    const u16* __restrict__ gi,          // [2][SB][768] bf16 prescaled, r/z b_hh folded
    const float* __restrict__ bhh,       // [6][2][768] f32 raw (n-gate term)
    const float* __restrict__ h0,        // [12][64][256] f32
    u16* __restrict__ outc,              // [SB][512] bf16 (scratch on last layer)
    float* __restrict__ finals,          // [12][64][256] f32
    int layer)
{
    int b0 = blockIdx.x * 16;
    int d  = blockIdx.y;
    int ld = layer * 2 + d;
    int tid = threadIdx.x;
    int wv = tid >> 6, lane = tid & 63;
    int lr = lane & 15;
    int lq = lane >> 4;
    int r0 = lq * 4;

    // h: [2][4096] f16; elem (row,k) at idx (k>>5)*512 + ((k>>3)&3)*128 + row*8 + (k&7)
    __shared__ alignas(16) _Float16 hT[2][4096];   // 16 KB
    __shared__ alignas(16) u16 gT[2][16][G3];      // 48 KB -> total 64 KiB exactly

    const _Float16* Wl = whh16 + (size_t)ld * G3 * HID;
    const u16* gid = gi + (size_t)d * (size_t)SB * G3;

    int c0 = wv * 16 + lr;
    int c1 = c0 + 128;

    // ---- persistent weight B-frags (192 VGPR), pinned against remat
    // order: 0=r(c0) 1=r(c1) 2=z(c0) 3=z(c1) 4=n(c0) 5=n(c1)
    f16x8 w[6][8];
#pragma unroll
    for (int kt = 0; kt < 8; kt++) {
        w[0][kt] = *reinterpret_cast<const f16x8*>(Wl + (size_t)(c0)       * HID + kt * 32 + lq * 8);
        w[1][kt] = *reinterpret_cast<const f16x8*>(Wl + (size_t)(c1)       * HID + kt * 32 + lq * 8);
        w[2][kt] = *reinterpret_cast<const f16x8*>(Wl + (size_t)(256 + c0) * HID + kt * 32 + lq * 8);
        w[3][kt] = *reinterpret_cast<const f16x8*>(Wl + (size_t)(256 + c1) * HID + kt * 32 + lq * 8);
        w[4][kt] = *reinterpret_cast<const f16x8*>(Wl + (size_t)(512 + c0) * HID + kt * 32 + lq * 8);
        w[5][kt] = *reinterpret_cast<const f16x8*>(Wl + (size_t)(512 + c1) * HID + kt * 32 + lq * 8);
#pragma unroll
        for (int i = 0; i < 6; i++) asm volatile("" : "+v"(w[i][kt]));
    }

    float bhn0 = bhh[(size_t)ld * G3 + 512 + c0] * (2.f * L2E);
    float bhn1 = bhh[(size_t)ld * G3 + 512 + c1] * (2.f * L2E);

    // ---- h0 -> hreg (f32) + hT[0]
    const int hwb0 = (c0 >> 3) * 128 + lq * 32 + (c0 & 7);   // +q*8; c1 adds +2048
    float hreg0[4], hreg1[4];
#pragma unroll
    for (int q = 0; q < 4; q++) {
        float hv0 = h0[(size_t)ld * BATCH * HID + (b0 + r0 + q) * HID + c0];
        float hv1 = h0[(size_t)ld * BATCH * HID + (b0 + r0 + q) * HID + c1];
        hreg0[q] = hv0; hreg1[q] = hv1;
        hT[0][hwb0 + q * 8] = (_Float16)hv0;
        hT[0][hwb0 + 2048 + q * 8] = (_Float16)hv1;
    }

    // ---- gi DMA: PROVEN R7 pattern — wave wv stages 3 KB (rows 2wv..2wv+1)
    auto dma_gi = [&](int s, int buf) {
        const char* src = (const char*)(gid + ((size_t)s * BATCH + b0) * G3);
        char* dst = (char*)&gT[buf][0][0];
#pragma unroll
        for (int i = 0; i < 3; i++) {
            int off = wv * 3072 + i * 1024;
            gload_lds16(src + off + lane * 16, dst + off);
        }
    };

    dma_gi(d ? (S_LEN - 1) : 0, 0);
    asm volatile("s_waitcnt vmcnt(0)" ::: "memory");
    __syncthreads();

    auto step_body = [&](int t, const int par) {
        int s = d ? (S_LEN - 1 - t) : t;
        // 1. issue next step's gi DMA; pin issue position before the MFMAs
        if (t + 1 < S_LEN) dma_gi(d ? (s - 1) : (s + 1), par ^ 1);
        __builtin_amdgcn_sched_barrier(0);

        // 2. gate matmul from hT[par]
        f32x4 acc[6] = {};
#pragma unroll
        for (int kt = 0; kt < 8; kt++) {
            f16x8 a = *(const f16x8*)&hT[par][kt * 512 + lq * 128 + lr * 8];
#pragma unroll
            for (int i = 0; i < 6; i++)
                acc[i] = __builtin_amdgcn_mfma_f32_16x16x32_f16(a, w[i][kt], acc[i], 0, 0, 0);
        }

        // 3. GRU update (all gates in-lane); h -> hT[par^1]; outc stores
        const u16* gb = &gT[par][r0][0];
        size_t ob = ((size_t)s * BATCH + b0 + r0) * D2 + d * HID;
#pragma unroll
        for (int q = 0; q < 4; q++) {
            const u16* gr = gb + q * G3;
            {
                float gir = bf2f(gr[c0]);
                float giz = bf2f(gr[256 + c0]);
                float gin = bf2f(gr[512 + c0]);
                float r = fast_rcp(1.f + fast_exp2(-(gir + acc[0][q])));
                float z = fast_rcp(1.f + fast_exp2(-(giz + acc[2][q])));
                float xn2 = gin + r * (acc[4][q] + bhn0);
                float n = 1.f - 2.f * fast_rcp(fast_exp2(xn2) + 1.f);
                float hn = n + z * (hreg0[q] - n);
                hreg0[q] = hn;
                hT[par ^ 1][hwb0 + q * 8] = (_Float16)hn;
                outc[ob + q * D2 + c0] = f2bf(hn);
            }
            {
                float gir = bf2f(gr[c1]);
                float giz = bf2f(gr[256 + c1]);
                float gin = bf2f(gr[512 + c1]);
                float r = fast_rcp(1.f + fast_exp2(-(gir + acc[1][q])));
                float z = fast_rcp(1.f + fast_exp2(-(giz + acc[3][q])));
                float xn2 = gin + r * (acc[5][q] + bhn1);
                float n = 1.f - 2.f * fast_rcp(fast_exp2(xn2) + 1.f);
                float hn = n + z * (hreg1[q] - n);
                hreg1[q] = hn;
                hT[par ^ 1][hwb0 + 2048 + q * 8] = (_Float16)hn;
                outc[ob + q * D2 + c1] = f2bf(hn);
            }
        }
        // 4. one barrier; vmcnt(8) drains the 3 gi DMAs (oldest) but not this
        //    step's 8 outc stores; lgkmcnt(0) covers h ds_writes + gi ds_reads.
        asm volatile("s_waitcnt vmcnt(8) lgkmcnt(0)" ::: "memory");
        __builtin_amdgcn_s_barrier();
        __builtin_amdgcn_sched_barrier(0);
    };

    for (int t2 = 0; t2 < S_LEN; t2 += 2) {
        step_body(t2, 0);
        step_body(t2 + 1, 1);
    }

#pragma unroll
    for (int q = 0; q < 4; q++) {
        finals[(size_t)ld * BATCH * HID + (b0 + r0 + q) * HID + c0] = hreg0[q];
        finals[(size_t)ld * BATCH * HID + (b0 + r0 + q) * HID + c1] = hreg1[q];
    }
}

extern "C" void kernel_launch(void* const* d_in, const int* in_sizes, int n_in,
                              void* d_out, int out_size, void* d_ws, size_t ws_size,
                              hipStream_t stream) {
    const float* x     = (const float*)d_in[0];
    const float* h0    = (const float*)d_in[1];
    const float* w_ih0 = (const float*)d_in[2];
    const float* b_ih0 = (const float*)d_in[3];
    const float* w_ih  = (const float*)d_in[4];
    const float* b_ih  = (const float*)d_in[5];
    const float* w_hh  = (const float*)d_in[6];
    const float* b_hh  = (const float*)d_in[7];
    float* out = (float*)d_out;

    char* ws = (char*)d_ws;
    // whh16 f16 [12][768][256]    @ 0            4,718,592
    // wbf0  bf16 [2][768][128]    @ 4,718,592      393,216
    // wbfl  bf16 [5][2][768][512] @ 5,111,808    7,864,320
    // biasT f32 [6][2][768]       @ 12,976,128      36,864
    // gi    bf16 [2][SB][768]     @ 13,012,992 100,663,296
    // curA  bf16 [SB][512]        @ 113,676,288 33,554,432
    // curB  bf16 [SB][512]        @ 147,230,720 33,554,432
    _Float16* whh16 = (_Float16*)(ws + 0);
    u16* wbf0  = (u16*)(ws + 4718592);
    u16* wbfl  = (u16*)(ws + 5111808);
    float* biasT = (float*)(ws + 12976128);
    u16* gi    = (u16*)(ws + 13012992);
    u16* curA  = (u16*)(ws + 113676288);
    u16* curB  = (u16*)(ws + 147230720);

    f32_to_f16_gs<<<(2359296 + 255) / 256, 256, 0, stream>>>(w_hh, whh16, 2359296L);
    f32_to_bf16_gs<<<(196608 + 255) / 256, 256, 0, stream>>>(w_ih0, wbf0, 196608L, 128);
    f32_to_bf16_gs<<<(3932160 + 255) / 256, 256, 0, stream>>>(w_ih, wbfl, 3932160L, 512);
    f32_to_bf16<<<(4194304 + 255) / 256, 256, 0, stream>>>(x, curA, 4194304L);
    add_bias<<<(9216 + 255) / 256, 256, 0, stream>>>(b_ih0, b_ih, b_hh, biasT);

    u16* cin = curA;
    u16* cout_ = curB;
    for (int l = 0; l < 6; l++) {
        int K = l ? 512 : 128;
        const u16* wt = l ? (wbfl + (size_t)(l - 1) * 2 * 768 * 512) : wbf0;
        const float* bi = biasT + (size_t)l * 1536;
        dim3 g(6, 256, 2);
        gemm_mfma<<<g, 256, 0, stream>>>(cin, wt, bi, gi, K);
        scan_mfma<<<dim3(4, 2), 512, 0, stream>>>(whh16, gi, b_hh, h0,
                                                  cout_, out, l);
        u16* tmp = cin; cin = cout_; cout_ = tmp;
    }
}